// Round 1
// 1385.330 us; speedup vs baseline: 1.1804x; 1.1804x over previous
//
#include <hip/hip_runtime.h>
#include <hip/hip_bf16.h>

#define SEQ   2048
#define NE    768
#define DI    1536
#define DS    16
#define DC    4
#define DTR   48
#define NL    2
#define VOCAB 32000
#define EPS   1e-5f
#define CHUNK 128
#define NCH   (SEQ / CHUNK)

typedef __hip_bfloat16 bf16;
typedef __bf16 bf16x8 __attribute__((ext_vector_type(8)));
typedef float  f32x4  __attribute__((ext_vector_type(4)));

#define GLOBAL_AS __attribute__((address_space(1)))
#define LDS_AS    __attribute__((address_space(3)))

// async global->LDS, 16 bytes per lane (global_load_lds_dwordx4)
__device__ __forceinline__ void gload16(const void* g, void* l)
{
    __builtin_amdgcn_global_load_lds((const GLOBAL_AS void*)g, (LDS_AS void*)l, 16, 0, 0);
}

// ---------------------------------------------------------------------------
// fp32 -> bf16 conversion (for MFMA weight operands). n % 4 == 0.
// ---------------------------------------------------------------------------
__global__ __launch_bounds__(256) void f2b_k(const float* __restrict__ x,
    bf16* __restrict__ y, int n)
{
    int i = (blockIdx.x * 256 + threadIdx.x) * 4;
    if (i >= n) return;
    float4 v = *reinterpret_cast<const float4*>(x + i);
    y[i + 0] = __float2bfloat16(v.x);
    y[i + 1] = __float2bfloat16(v.y);
    y[i + 2] = __float2bfloat16(v.z);
    y[i + 3] = __float2bfloat16(v.w);
}

// ---------------------------------------------------------------------------
// Embedding gather: h[l,:] = E[tokens[l],:]  (fp32 in/out)
// ---------------------------------------------------------------------------
__global__ __launch_bounds__(256) void embed_k(const int* __restrict__ tok,
    const float* __restrict__ E, float* __restrict__ h)
{
    int l = blockIdx.x;
    int t = tok[l];
    for (int k = threadIdx.x; k < NE; k += 256)
        h[(size_t)l * NE + k] = E[(size_t)t * NE + k];
}

// ---------------------------------------------------------------------------
// RMSNorm over last dim (768), bf16 out for MFMA consumption
// ---------------------------------------------------------------------------
__global__ __launch_bounds__(256) void rmsnorm_k(const float* __restrict__ x,
    const float* __restrict__ w, const float* __restrict__ b, bf16* __restrict__ out)
{
    int l = blockIdx.x;
    const float* xr = x + (size_t)l * NE;
    float ss = 0.f;
    for (int k = threadIdx.x; k < NE; k += 256) { float v = xr[k]; ss += v * v; }
    for (int o = 32; o; o >>= 1) ss += __shfl_down(ss, o);
    __shared__ float s4[4];
    if ((threadIdx.x & 63) == 0) s4[threadIdx.x >> 6] = ss;
    __syncthreads();
    float inv = rsqrtf((s4[0] + s4[1] + s4[2] + s4[3]) / NE + EPS);
    for (int k = threadIdx.x; k < NE; k += 256)
        out[(size_t)l * NE + k] = __float2bfloat16(xr[k] * inv * w[k] + b[k]);
}

// ---------------------------------------------------------------------------
// MFMA GEMM: C[M,N] = A[M,K] @ B[N,K]^T, bf16 inputs, fp32 accum, fp32 out.
// m97 structure: 128x128 block tile, BK=32, LDS staging via
// global_load_lds width=16, 2-barrier K-loop, ds_read_b128 fragments.
// Block 256 thr = 4 waves in 2x2; wave tile 64x64 (4x4 of 16x16x32 MFMA).
// Requires M%128==0, N%128==0, K%32==0.
// ---------------------------------------------------------------------------
__global__ __launch_bounds__(256) void gemm_bt(const bf16* __restrict__ Abf,
    const bf16* __restrict__ Bbf, float* __restrict__ Cout, int M, int N, int K)
{
    // 128 rows x 32 cols bf16, row-major, 64 B/row, 8 KB each
    __shared__ __align__(16) __bf16 As[128 * 32];
    __shared__ __align__(16) __bf16 Bs[128 * 32];

    const int tid  = threadIdx.x;
    const int wave = tid >> 6;
    const int lane = tid & 63;
    const int wm = wave >> 1, wn = wave & 1;
    const int tm = blockIdx.y * 128;
    const int tn = blockIdx.x * 128;
    const int r16 = lane & 15, quad = lane >> 4;

    const __bf16* A = reinterpret_cast<const __bf16*>(Abf);
    const __bf16* B = reinterpret_cast<const __bf16*>(Bbf);

    // Staging: tile is 512 x 16B chunks; 256 threads x 2 chunks per matrix.
    // Chunk c: row = c>>2, col-chunk = (c&3)*8 bf16. LDS dest = c*16 bytes,
    // which is (wave-uniform base) + lane*16 for c = j*256 + wave*64 + lane.
    const int c0 = tid, c1 = tid + 256;
    const __bf16* ga0 = A + (size_t)(tm + (c0 >> 2)) * K + (c0 & 3) * 8;
    const __bf16* ga1 = A + (size_t)(tm + (c1 >> 2)) * K + (c1 & 3) * 8;
    const __bf16* gb0 = B + (size_t)(tn + (c0 >> 2)) * K + (c0 & 3) * 8;
    const __bf16* gb1 = B + (size_t)(tn + (c1 >> 2)) * K + (c1 & 3) * 8;
    __bf16* la0 = As + c0 * 8;
    __bf16* la1 = As + c1 * 8;
    __bf16* lb0 = Bs + c0 * 8;
    __bf16* lb1 = Bs + c1 * 8;

    f32x4 zero = {0.f, 0.f, 0.f, 0.f};
    f32x4 acc[4][4];
#pragma unroll
    for (int i = 0; i < 4; i++)
#pragma unroll
        for (int j = 0; j < 4; j++) acc[i][j] = zero;

    // fragment read bases (elements): row*32 + quad*8
    const int arow = wm * 64 + r16;
    const int brow = wn * 64 + r16;

    for (int kt = 0; kt < K; kt += 32) {
        __syncthreads();                 // all waves done reading previous tile
        gload16(ga0 + kt, la0);
        gload16(ga1 + kt, la1);
        gload16(gb0 + kt, lb0);
        gload16(gb1 + kt, lb1);
        __syncthreads();                 // drains vmcnt -> LDS tile ready

        bf16x8 av[4], bv[4];
#pragma unroll
        for (int i = 0; i < 4; i++)
            av[i] = *reinterpret_cast<const bf16x8*>(As + (arow + i * 16) * 32 + quad * 8);
#pragma unroll
        for (int j = 0; j < 4; j++)
            bv[j] = *reinterpret_cast<const bf16x8*>(Bs + (brow + j * 16) * 32 + quad * 8);
#pragma unroll
        for (int i = 0; i < 4; i++)
#pragma unroll
            for (int j = 0; j < 4; j++)
                acc[i][j] = __builtin_amdgcn_mfma_f32_16x16x32_bf16(av[i], bv[j], acc[i][j], 0, 0, 0);
    }

#pragma unroll
    for (int i = 0; i < 4; i++) {
        int cm0 = tm + wm * 64 + i * 16 + quad * 4;
#pragma unroll
        for (int j = 0; j < 4; j++) {
            int cn = tn + wn * 64 + j * 16 + r16;
#pragma unroll
            for (int r = 0; r < 4; r++)
                Cout[(size_t)(cm0 + r) * N + cn] = acc[i][j][r];
        }
    }
}

// ---------------------------------------------------------------------------
// Depthwise causal conv (k=4) + bias + SiLU.
// ---------------------------------------------------------------------------
__global__ __launch_bounds__(256) void conv_silu_k(const float* __restrict__ xr,
    const float* __restrict__ cw, const float* __restrict__ cb, float* __restrict__ u)
{
    int idx = blockIdx.x * 256 + threadIdx.x;   // over SEQ*DI
    int l = idx / DI, d = idx - l * DI;
    float s = cb[d];
#pragma unroll
    for (int t = 0; t < DC; t++) {
        int ls = l - (DC - 1) + t;
        if (ls >= 0) s += xr[(size_t)ls * (2 * DI) + d] * cw[d * DC + t];
    }
    u[idx] = s / (1.f + expf(-s));
}

// ---------------------------------------------------------------------------
// x_proj: xdbl[l, j] = sum_k u[l,k] * xpw[j,k], j < 80. One wave per (l,j).
// ---------------------------------------------------------------------------
__global__ __launch_bounds__(256) void xproj_k(const float* __restrict__ u,
    const float* __restrict__ xpw, float* __restrict__ xdbl)
{
    int gw = blockIdx.x * 4 + (threadIdx.x >> 6);
    int l = gw / 80, j = gw - l * 80;
    int lane = threadIdx.x & 63;
    const float* ur = u + (size_t)l * DI;
    const float* wr = xpw + (size_t)j * DI;
    float s = 0.f;
    for (int k = lane; k < DI; k += 64) s += ur[k] * wr[k];
    for (int o = 32; o; o >>= 1) s += __shfl_down(s, o);
    if (lane == 0) xdbl[(size_t)l * 80 + j] = s;
}

// ---------------------------------------------------------------------------
// dt_proj + softplus
// ---------------------------------------------------------------------------
__global__ __launch_bounds__(256) void dtproj_k(const float* __restrict__ xdbl,
    const float* __restrict__ dtw, const float* __restrict__ dtb, float* __restrict__ delta)
{
    int l = blockIdx.y;
    int d = blockIdx.x * 256 + threadIdx.x;
    __shared__ float xs[DTR];
    if (threadIdx.x < DTR) xs[threadIdx.x] = xdbl[(size_t)l * 80 + threadIdx.x];
    __syncthreads();
    float s = dtb[d];
    const float* wr = dtw + (size_t)d * DTR;
#pragma unroll
    for (int k = 0; k < DTR; k++) s += xs[k] * wr[k];
    delta[(size_t)l * DI + d] = fmaxf(s, 0.f) + log1pf(expf(-fabsf(s)));
}

// ---------------------------------------------------------------------------
// Chunked selective scan, pass 1: per chunk c, per (d,n): local end-state S
// (from zero init) and decay product P = prod(exp(delta*A)) over the chunk.
// Grid (DI/16, NCH), block 256 = 16 d-groups x 16 n.
// ---------------------------------------------------------------------------
__global__ __launch_bounds__(256) void scan1_k(const float* __restrict__ delta,
    const float* __restrict__ u, const float* __restrict__ xdbl,
    const float* __restrict__ alog, float* __restrict__ S, float* __restrict__ P)
{
    int dg = threadIdx.x >> 4, n = threadIdx.x & 15;
    int d = blockIdx.x * 16 + dg;
    int c = blockIdx.y;
    float A = -expf(alog[(size_t)d * DS + n]);
    float st = 0.f, pr = 1.f;
    int l0 = c * CHUNK;
#pragma unroll 4
    for (int t = 0; t < CHUNK; t++) {
        int l = l0 + t;
        float dl = delta[(size_t)l * DI + d];
        float ul = u[(size_t)l * DI + d];
        float Bn = xdbl[(size_t)l * 80 + DTR + n];
        float a = expf(dl * A);
        st = a * st + dl * ul * Bn;
        pr *= a;
    }
    size_t o = ((size_t)c * DI + d) * DS + n;
    S[o] = st;
    P[o] = pr;
}

// ---------------------------------------------------------------------------
// Pass 2: sequential combine over the 16 chunks -> incoming state per chunk.
// 96 blocks x 256 threads, thread = flat (d,n).
// ---------------------------------------------------------------------------
__global__ __launch_bounds__(256) void scan2_k(const float* __restrict__ S,
    const float* __restrict__ P, float* __restrict__ sin_)
{
    int i = blockIdx.x * 256 + threadIdx.x;   // over DI*DS
    float run = 0.f;
#pragma unroll
    for (int c = 0; c < NCH; c++) {
        size_t o = (size_t)c * DI * DS + i;
        sin_[o] = run;
        run = S[o] + P[o] * run;
    }
}

// ---------------------------------------------------------------------------
// Pass 3: re-run each chunk from its incoming state, compute y, fuse
// (y + u*D) * silu(res) gate, write bf16 for the out_proj GEMM.
// ---------------------------------------------------------------------------
__global__ __launch_bounds__(256) void scan3_k(const float* __restrict__ delta,
    const float* __restrict__ u, const float* __restrict__ xdbl,
    const float* __restrict__ alog, const float* __restrict__ sin_,
    const float* __restrict__ Dp, const float* __restrict__ xr,
    bf16* __restrict__ ybf)
{
    int dg = threadIdx.x >> 4, n = threadIdx.x & 15;
    int d = blockIdx.x * 16 + dg;
    int c = blockIdx.y;
    float A = -expf(alog[(size_t)d * DS + n]);
    float Dv = Dp[d];
    float st = sin_[((size_t)c * DI + d) * DS + n];
    int l0 = c * CHUNK;
#pragma unroll 2
    for (int t = 0; t < CHUNK; t++) {
        int l = l0 + t;
        float dl = delta[(size_t)l * DI + d];
        float ul = u[(size_t)l * DI + d];
        float Bn = xdbl[(size_t)l * 80 + DTR + n];
        float Cn = xdbl[(size_t)l * 80 + DTR + DS + n];
        float a = expf(dl * A);
        st = a * st + dl * ul * Bn;
        float p = st * Cn;
        p += __shfl_down(p, 8);
        p += __shfl_down(p, 4);
        p += __shfl_down(p, 2);
        p += __shfl_down(p, 1);
        if (n == 0) {
            float r = xr[(size_t)l * (2 * DI) + DI + d];
            float yv = (p + ul * Dv) * (r / (1.f + expf(-r)));
            ybf[(size_t)l * DI + d] = __float2bfloat16(yv);
        }
    }
}

// ---------------------------------------------------------------------------
// h += tmp
// ---------------------------------------------------------------------------
__global__ __launch_bounds__(256) void add_k(float* __restrict__ h, const float* __restrict__ t)
{
    int i = blockIdx.x * 256 + threadIdx.x;
    h[i] += t[i];
}

// ---------------------------------------------------------------------------
extern "C" void kernel_launch(void* const* d_in, const int* in_sizes, int n_in,
                              void* d_out, int out_size, void* d_ws, size_t ws_size,
                              hipStream_t stream)
{
    const int*   tokens  = (const int*)  d_in[0];
    const float* E       = (const float*)d_in[1];
    const float* in_w    = (const float*)d_in[2];
    const float* conv_w  = (const float*)d_in[3];
    const float* conv_b  = (const float*)d_in[4];
    const float* xp_w    = (const float*)d_in[5];
    const float* dt_w    = (const float*)d_in[6];
    const float* dt_b    = (const float*)d_in[7];
    const float* A_log   = (const float*)d_in[8];
    const float* D_p     = (const float*)d_in[9];
    const float* out_w   = (const float*)d_in[10];
    const float* norm_w  = (const float*)d_in[11];
    const float* norm_b  = (const float*)d_in[12];
    const float* normf_w = (const float*)d_in[13];
    const float* normf_b = (const float*)d_in[14];

    char* ws = (char*)d_ws;
    size_t off = 0;
    auto alloc = [&](size_t bytes) -> void* {
        void* p = ws + off;
        off = (off + bytes + 255) & ~(size_t)255;
        return p;
    };

    float* h     = (float*)alloc((size_t)SEQ * NE * 4);
    bf16*  xn    = (bf16*) alloc((size_t)SEQ * NE * 2);
    float* xr    = (float*)alloc((size_t)SEQ * 2 * DI * 4);
    float* u     = (float*)alloc((size_t)SEQ * DI * 4);
    float* xdbl  = (float*)alloc((size_t)SEQ * 80 * 4);
    float* delta = (float*)alloc((size_t)SEQ * DI * 4);
    bf16*  ybf   = (bf16*) alloc((size_t)SEQ * DI * 2);
    float* tmp   = (float*)alloc((size_t)SEQ * NE * 4);
    bf16*  hf    = (bf16*) alloc((size_t)SEQ * NE * 2);
    bf16*  Ebf   = (bf16*) alloc((size_t)VOCAB * NE * 2);           // 49 MB
    bf16*  wbuf  = (bf16*) alloc((size_t)2 * DI * NE * 2);          // reused proj weights
    float* Sbuf  = (float*)alloc((size_t)NCH * DI * DS * 4);
    float* Pbuf  = (float*)alloc((size_t)NCH * DI * DS * 4);
    float* Sin   = (float*)alloc((size_t)NCH * DI * DS * 4);

    {
        int n = VOCAB * NE;
        f2b_k<<<(n / 4 + 255) / 256, 256, 0, stream>>>(E, Ebf, n);
    }

    embed_k<<<SEQ, 256, 0, stream>>>(tokens, E, h);

    for (int L = 0; L < NL; L++) {
        rmsnorm_k<<<SEQ, 256, 0, stream>>>(h, norm_w + (size_t)L * NE, norm_b + (size_t)L * NE, xn);

        {
            int n = 2 * DI * NE;
            f2b_k<<<(n / 4 + 255) / 256, 256, 0, stream>>>(in_w + (size_t)L * n, wbuf, n);
        }
        gemm_bt<<<dim3(2 * DI / 128, SEQ / 128), 256, 0, stream>>>(
            xn, wbuf, xr, SEQ, 2 * DI, NE);

        conv_silu_k<<<SEQ * DI / 256, 256, 0, stream>>>(
            xr, conv_w + (size_t)L * DI * DC, conv_b + (size_t)L * DI, u);

        xproj_k<<<SEQ * 80 / 4, 256, 0, stream>>>(u, xp_w + (size_t)L * 80 * DI, xdbl);

        dtproj_k<<<dim3(DI / 256, SEQ), 256, 0, stream>>>(
            xdbl, dt_w + (size_t)L * DI * DTR, dt_b + (size_t)L * DI, delta);

        const float* alog = A_log + (size_t)L * DI * DS;
        scan1_k<<<dim3(DI / 16, NCH), 256, 0, stream>>>(delta, u, xdbl, alog, Sbuf, Pbuf);
        scan2_k<<<DI * DS / 256, 256, 0, stream>>>(Sbuf, Pbuf, Sin);
        scan3_k<<<dim3(DI / 16, NCH), 256, 0, stream>>>(
            delta, u, xdbl, alog, Sin, D_p + (size_t)L * DI, xr, ybf);

        {
            int n = NE * DI;
            f2b_k<<<(n / 4 + 255) / 256, 256, 0, stream>>>(out_w + (size_t)L * n, wbuf, n);
        }
        gemm_bt<<<dim3(NE / 128, SEQ / 128), 256, 0, stream>>>(
            ybf, wbuf, tmp, SEQ, NE, DI);

        add_k<<<SEQ * NE / 256, 256, 0, stream>>>(h, tmp);
    }

    rmsnorm_k<<<SEQ, 256, 0, stream>>>(h, normf_w, normf_b, hf);

    gemm_bt<<<dim3(VOCAB / 128, SEQ / 128), 256, 0, stream>>>(
        hf, Ebf, (float*)d_out, SEQ, VOCAB, NE);
}

// Round 2
// 1193.899 us; speedup vs baseline: 1.3697x; 1.1603x over previous
//
#include <hip/hip_runtime.h>
#include <hip/hip_bf16.h>

#define SEQ   2048
#define NE    768
#define DI    1536
#define DS    16
#define DC    4
#define DTR   48
#define NL    2
#define VOCAB 32000
#define EPS   1e-5f
#define CHUNK 128
#define NCH   (SEQ / CHUNK)

typedef __hip_bfloat16 bf16;
typedef __bf16 bf16x8 __attribute__((ext_vector_type(8)));
typedef float  f32x4  __attribute__((ext_vector_type(4)));

#define GLOBAL_AS __attribute__((address_space(1)))
#define LDS_AS    __attribute__((address_space(3)))

// async global->LDS, 16 bytes per lane (global_load_lds_dwordx4)
__device__ __forceinline__ void gload16(const void* g, void* l)
{
    __builtin_amdgcn_global_load_lds((const GLOBAL_AS void*)g, (LDS_AS void*)l, 16, 0, 0);
}

// ---------------------------------------------------------------------------
// fp32 -> bf16 conversion (for MFMA weight operands). n % 4 == 0.
// ---------------------------------------------------------------------------
__global__ __launch_bounds__(256) void f2b_k(const float* __restrict__ x,
    bf16* __restrict__ y, int n)
{
    int i = (blockIdx.x * 256 + threadIdx.x) * 4;
    if (i >= n) return;
    float4 v = *reinterpret_cast<const float4*>(x + i);
    y[i + 0] = __float2bfloat16(v.x);
    y[i + 1] = __float2bfloat16(v.y);
    y[i + 2] = __float2bfloat16(v.z);
    y[i + 3] = __float2bfloat16(v.w);
}

// ---------------------------------------------------------------------------
// Embedding gather: h[l,:] = E[tokens[l],:]  (fp32 in/out)
// ---------------------------------------------------------------------------
__global__ __launch_bounds__(256) void embed_k(const int* __restrict__ tok,
    const float* __restrict__ E, float* __restrict__ h)
{
    int l = blockIdx.x;
    int t = tok[l];
    for (int k = threadIdx.x; k < NE; k += 256)
        h[(size_t)l * NE + k] = E[(size_t)t * NE + k];
}

// ---------------------------------------------------------------------------
// RMSNorm over last dim (768), bf16 out for MFMA consumption
// ---------------------------------------------------------------------------
__global__ __launch_bounds__(256) void rmsnorm_k(const float* __restrict__ x,
    const float* __restrict__ w, const float* __restrict__ b, bf16* __restrict__ out)
{
    int l = blockIdx.x;
    const float* xr = x + (size_t)l * NE;
    float ss = 0.f;
    for (int k = threadIdx.x; k < NE; k += 256) { float v = xr[k]; ss += v * v; }
    for (int o = 32; o; o >>= 1) ss += __shfl_down(ss, o);
    __shared__ float s4[4];
    if ((threadIdx.x & 63) == 0) s4[threadIdx.x >> 6] = ss;
    __syncthreads();
    float inv = rsqrtf((s4[0] + s4[1] + s4[2] + s4[3]) / NE + EPS);
    for (int k = threadIdx.x; k < NE; k += 256)
        out[(size_t)l * NE + k] = __float2bfloat16(xr[k] * inv * w[k] + b[k]);
}

// ---------------------------------------------------------------------------
// MFMA GEMM: C[M,N] = A[M,K] @ B[N,K]^T, bf16 inputs, fp32 accum, fp32 out.
// m97 structure (128x128 tile, BK=32, global_load_lds w=16, 2-barrier loop)
// + 1D grid with M-inner ordering and bijective XCD swizzle: each XCD's
// contiguous chunk of blocks walks all M for a run of N-panels, so each
// B-panel is fetched once per XCD and A stays L2-resident.
// accum: 0 -> C = A@B^T ; 1 -> C += A@B^T.
// Requires M%128==0, N%128==0, K%32==0. Launch with nwg=(M/128)*(N/128).
// ---------------------------------------------------------------------------
__global__ __launch_bounds__(256) void gemm_bt(const bf16* __restrict__ Abf,
    const bf16* __restrict__ Bbf, float* __restrict__ Cout, int M, int N, int K,
    int accum)
{
    __shared__ __align__(16) __bf16 As[128 * 32];
    __shared__ __align__(16) __bf16 Bs[128 * 32];

    // bijective XCD swizzle (m204): orig%8 is the HW round-robin XCD.
    const int nwg = gridDim.x;
    const int bid = blockIdx.x;
    const int q = nwg >> 3, r = nwg & 7;
    const int xcd = bid & 7, loc = bid >> 3;
    const int swz = (xcd < r ? xcd * (q + 1) : r * (q + 1) + (xcd - r) * q) + loc;
    // M-inner: consecutive swz share a B-panel
    const int mb = M >> 7;
    const int npan = swz / mb;
    const int mpan = swz - npan * mb;
    const int tm = mpan * 128;
    const int tn = npan * 128;

    const int tid  = threadIdx.x;
    const int wave = tid >> 6;
    const int lane = tid & 63;
    const int wm = wave >> 1, wn = wave & 1;
    const int r16 = lane & 15, quad = lane >> 4;

    const __bf16* A = reinterpret_cast<const __bf16*>(Abf);
    const __bf16* B = reinterpret_cast<const __bf16*>(Bbf);

    // Staging: tile is 512 x 16B chunks; 256 threads x 2 chunks per matrix.
    const int c0 = tid, c1 = tid + 256;
    const __bf16* ga0 = A + (size_t)(tm + (c0 >> 2)) * K + (c0 & 3) * 8;
    const __bf16* ga1 = A + (size_t)(tm + (c1 >> 2)) * K + (c1 & 3) * 8;
    const __bf16* gb0 = B + (size_t)(tn + (c0 >> 2)) * K + (c0 & 3) * 8;
    const __bf16* gb1 = B + (size_t)(tn + (c1 >> 2)) * K + (c1 & 3) * 8;
    __bf16* la0 = As + c0 * 8;
    __bf16* la1 = As + c1 * 8;
    __bf16* lb0 = Bs + c0 * 8;
    __bf16* lb1 = Bs + c1 * 8;

    f32x4 zero = {0.f, 0.f, 0.f, 0.f};
    f32x4 acc[4][4];
#pragma unroll
    for (int i = 0; i < 4; i++)
#pragma unroll
        for (int j = 0; j < 4; j++) acc[i][j] = zero;

    const int arow = wm * 64 + r16;
    const int brow = wn * 64 + r16;

    for (int kt = 0; kt < K; kt += 32) {
        __syncthreads();
        gload16(ga0 + kt, la0);
        gload16(ga1 + kt, la1);
        gload16(gb0 + kt, lb0);
        gload16(gb1 + kt, lb1);
        __syncthreads();

        bf16x8 av[4], bv[4];
#pragma unroll
        for (int i = 0; i < 4; i++)
            av[i] = *reinterpret_cast<const bf16x8*>(As + (arow + i * 16) * 32 + quad * 8);
#pragma unroll
        for (int j = 0; j < 4; j++)
            bv[j] = *reinterpret_cast<const bf16x8*>(Bs + (brow + j * 16) * 32 + quad * 8);
#pragma unroll
        for (int i = 0; i < 4; i++)
#pragma unroll
            for (int j = 0; j < 4; j++)
                acc[i][j] = __builtin_amdgcn_mfma_f32_16x16x32_bf16(av[i], bv[j], acc[i][j], 0, 0, 0);
    }

#pragma unroll
    for (int i = 0; i < 4; i++) {
        int cm0 = tm + wm * 64 + i * 16 + quad * 4;
#pragma unroll
        for (int j = 0; j < 4; j++) {
            int cn = tn + wn * 64 + j * 16 + r16;
            if (accum) {
#pragma unroll
                for (int rr = 0; rr < 4; rr++)
                    Cout[(size_t)(cm0 + rr) * N + cn] += acc[i][j][rr];
            } else {
#pragma unroll
                for (int rr = 0; rr < 4; rr++)
                    Cout[(size_t)(cm0 + rr) * N + cn] = acc[i][j][rr];
            }
        }
    }
}

// ---------------------------------------------------------------------------
// Depthwise causal conv (k=4) + bias + SiLU.
// ---------------------------------------------------------------------------
__global__ __launch_bounds__(256) void conv_silu_k(const float* __restrict__ xr,
    const float* __restrict__ cw, const float* __restrict__ cb, float* __restrict__ u)
{
    int idx = blockIdx.x * 256 + threadIdx.x;   // over SEQ*DI
    int l = idx / DI, d = idx - l * DI;
    float s = cb[d];
#pragma unroll
    for (int t = 0; t < DC; t++) {
        int ls = l - (DC - 1) + t;
        if (ls >= 0) s += xr[(size_t)ls * (2 * DI) + d] * cw[d * DC + t];
    }
    u[idx] = s / (1.f + expf(-s));
}

// ---------------------------------------------------------------------------
// x_proj: xdbl[l, j] = sum_k u[l,k] * xpw[j,k], j < 80. One wave per (l,j).
// float4 vectorized loads (16 B/lane).
// ---------------------------------------------------------------------------
__global__ __launch_bounds__(256) void xproj_k(const float* __restrict__ u,
    const float* __restrict__ xpw, float* __restrict__ xdbl)
{
    int gw = blockIdx.x * 4 + (threadIdx.x >> 6);
    int l = gw / 80, j = gw - l * 80;
    int lane = threadIdx.x & 63;
    const float4* ur = reinterpret_cast<const float4*>(u + (size_t)l * DI);
    const float4* wr = reinterpret_cast<const float4*>(xpw + (size_t)j * DI);
    float s = 0.f;
#pragma unroll
    for (int k = lane; k < DI / 4; k += 64) {
        float4 a = ur[k], b = wr[k];
        s += a.x * b.x + a.y * b.y + a.z * b.z + a.w * b.w;
    }
    for (int o = 32; o; o >>= 1) s += __shfl_down(s, o);
    if (lane == 0) xdbl[(size_t)l * 80 + j] = s;
}

// ---------------------------------------------------------------------------
// dt_proj + softplus. Weights held in registers (48/thread); each block owns
// 256 d-channels and loops 32 sequence rows, sharing xs[48] via LDS.
// Grid (DI/256, SEQ/32).
// ---------------------------------------------------------------------------
__global__ __launch_bounds__(256) void dtproj_k(const float* __restrict__ xdbl,
    const float* __restrict__ dtw, const float* __restrict__ dtb, float* __restrict__ delta)
{
    int d = blockIdx.x * 256 + threadIdx.x;
    float w[DTR];
    const float* wr = dtw + (size_t)d * DTR;
#pragma unroll
    for (int k = 0; k < DTR; k++) w[k] = wr[k];
    float bv = dtb[d];
    __shared__ float xs[DTR];
    int l0 = blockIdx.y * 32;
    for (int li = 0; li < 32; li++) {
        int l = l0 + li;
        __syncthreads();
        if (threadIdx.x < DTR) xs[threadIdx.x] = xdbl[(size_t)l * 80 + threadIdx.x];
        __syncthreads();
        float s = bv;
#pragma unroll
        for (int k = 0; k < DTR; k++) s += xs[k] * w[k];
        delta[(size_t)l * DI + d] = fmaxf(s, 0.f) + log1pf(expf(-fabsf(s)));
    }
}

// ---------------------------------------------------------------------------
// Chunked selective scan, pass 1: per chunk c, per (d,n): local end-state S
// (from zero init) and decay product P = prod(exp(delta*A)) over the chunk.
// Grid (DI/16, NCH), block 256 = 16 d-groups x 16 n.
// ---------------------------------------------------------------------------
__global__ __launch_bounds__(256) void scan1_k(const float* __restrict__ delta,
    const float* __restrict__ u, const float* __restrict__ xdbl,
    const float* __restrict__ alog, float* __restrict__ S, float* __restrict__ P)
{
    int dg = threadIdx.x >> 4, n = threadIdx.x & 15;
    int d = blockIdx.x * 16 + dg;
    int c = blockIdx.y;
    float A = -expf(alog[(size_t)d * DS + n]);
    float st = 0.f, pr = 1.f;
    int l0 = c * CHUNK;
#pragma unroll 4
    for (int t = 0; t < CHUNK; t++) {
        int l = l0 + t;
        float dl = delta[(size_t)l * DI + d];
        float ul = u[(size_t)l * DI + d];
        float Bn = xdbl[(size_t)l * 80 + DTR + n];
        float a = expf(dl * A);
        st = a * st + dl * ul * Bn;
        pr *= a;
    }
    size_t o = ((size_t)c * DI + d) * DS + n;
    S[o] = st;
    P[o] = pr;
}

// ---------------------------------------------------------------------------
// Pass 2: sequential combine over the 16 chunks -> incoming state per chunk.
// 96 blocks x 256 threads, thread = flat (d,n).
// ---------------------------------------------------------------------------
__global__ __launch_bounds__(256) void scan2_k(const float* __restrict__ S,
    const float* __restrict__ P, float* __restrict__ sin_)
{
    int i = blockIdx.x * 256 + threadIdx.x;   // over DI*DS
    float run = 0.f;
#pragma unroll
    for (int c = 0; c < NCH; c++) {
        size_t o = (size_t)c * DI * DS + i;
        sin_[o] = run;
        run = S[o] + P[o] * run;
    }
}

// ---------------------------------------------------------------------------
// Pass 3: re-run each chunk from its incoming state, compute y, fuse
// (y + u*D) * silu(res) gate, write bf16 for the out_proj GEMM.
// ---------------------------------------------------------------------------
__global__ __launch_bounds__(256) void scan3_k(const float* __restrict__ delta,
    const float* __restrict__ u, const float* __restrict__ xdbl,
    const float* __restrict__ alog, const float* __restrict__ sin_,
    const float* __restrict__ Dp, const float* __restrict__ xr,
    bf16* __restrict__ ybf)
{
    int dg = threadIdx.x >> 4, n = threadIdx.x & 15;
    int d = blockIdx.x * 16 + dg;
    int c = blockIdx.y;
    float A = -expf(alog[(size_t)d * DS + n]);
    float Dv = Dp[d];
    float st = sin_[((size_t)c * DI + d) * DS + n];
    int l0 = c * CHUNK;
#pragma unroll 2
    for (int t = 0; t < CHUNK; t++) {
        int l = l0 + t;
        float dl = delta[(size_t)l * DI + d];
        float ul = u[(size_t)l * DI + d];
        float Bn = xdbl[(size_t)l * 80 + DTR + n];
        float Cn = xdbl[(size_t)l * 80 + DTR + DS + n];
        float a = expf(dl * A);
        st = a * st + dl * ul * Bn;
        float p = st * Cn;
        p += __shfl_down(p, 8);
        p += __shfl_down(p, 4);
        p += __shfl_down(p, 2);
        p += __shfl_down(p, 1);
        if (n == 0) {
            float r = xr[(size_t)l * (2 * DI) + DI + d];
            float yv = (p + ul * Dv) * (r / (1.f + expf(-r)));
            ybf[(size_t)l * DI + d] = __float2bfloat16(yv);
        }
    }
}

// ---------------------------------------------------------------------------
extern "C" void kernel_launch(void* const* d_in, const int* in_sizes, int n_in,
                              void* d_out, int out_size, void* d_ws, size_t ws_size,
                              hipStream_t stream)
{
    const int*   tokens  = (const int*)  d_in[0];
    const float* E       = (const float*)d_in[1];
    const float* in_w    = (const float*)d_in[2];
    const float* conv_w  = (const float*)d_in[3];
    const float* conv_b  = (const float*)d_in[4];
    const float* xp_w    = (const float*)d_in[5];
    const float* dt_w    = (const float*)d_in[6];
    const float* dt_b    = (const float*)d_in[7];
    const float* A_log   = (const float*)d_in[8];
    const float* D_p     = (const float*)d_in[9];
    const float* out_w   = (const float*)d_in[10];
    const float* norm_w  = (const float*)d_in[11];
    const float* norm_b  = (const float*)d_in[12];
    const float* normf_w = (const float*)d_in[13];
    const float* normf_b = (const float*)d_in[14];

    char* ws = (char*)d_ws;
    size_t off = 0;
    auto alloc = [&](size_t bytes) -> void* {
        void* p = ws + off;
        off = (off + bytes + 255) & ~(size_t)255;
        return p;
    };

    float* h     = (float*)alloc((size_t)SEQ * NE * 4);
    bf16*  xn    = (bf16*) alloc((size_t)SEQ * NE * 2);
    float* xr    = (float*)alloc((size_t)SEQ * 2 * DI * 4);
    float* u     = (float*)alloc((size_t)SEQ * DI * 4);
    float* xdbl  = (float*)alloc((size_t)SEQ * 80 * 4);
    float* delta = (float*)alloc((size_t)SEQ * DI * 4);
    bf16*  ybf   = (bf16*) alloc((size_t)SEQ * DI * 2);
    bf16*  hf    = (bf16*) alloc((size_t)SEQ * NE * 2);
    bf16*  Ebf   = (bf16*) alloc((size_t)VOCAB * NE * 2);           // 49 MB
    bf16*  wbuf  = (bf16*) alloc((size_t)2 * DI * NE * 2);          // reused proj weights
    float* Sbuf  = (float*)alloc((size_t)NCH * DI * DS * 4);
    float* Pbuf  = (float*)alloc((size_t)NCH * DI * DS * 4);
    float* Sin   = (float*)alloc((size_t)NCH * DI * DS * 4);

    {
        int n = VOCAB * NE;
        f2b_k<<<(n / 4 + 255) / 256, 256, 0, stream>>>(E, Ebf, n);
    }

    embed_k<<<SEQ, 256, 0, stream>>>(tokens, E, h);

    for (int L = 0; L < NL; L++) {
        rmsnorm_k<<<SEQ, 256, 0, stream>>>(h, norm_w + (size_t)L * NE, norm_b + (size_t)L * NE, xn);

        {
            int n = 2 * DI * NE;
            f2b_k<<<(n / 4 + 255) / 256, 256, 0, stream>>>(in_w + (size_t)L * n, wbuf, n);
        }
        gemm_bt<<<(2 * DI / 128) * (SEQ / 128), 256, 0, stream>>>(
            xn, wbuf, xr, SEQ, 2 * DI, NE, 0);

        conv_silu_k<<<SEQ * DI / 256, 256, 0, stream>>>(
            xr, conv_w + (size_t)L * DI * DC, conv_b + (size_t)L * DI, u);

        xproj_k<<<SEQ * 80 / 4, 256, 0, stream>>>(u, xp_w + (size_t)L * 80 * DI, xdbl);

        dtproj_k<<<dim3(DI / 256, SEQ / 32), 256, 0, stream>>>(
            xdbl, dt_w + (size_t)L * DI * DTR, dt_b + (size_t)L * DI, delta);

        const float* alog = A_log + (size_t)L * DI * DS;
        scan1_k<<<dim3(DI / 16, NCH), 256, 0, stream>>>(delta, u, xdbl, alog, Sbuf, Pbuf);
        scan2_k<<<DI * DS / 256, 256, 0, stream>>>(Sbuf, Pbuf, Sin);
        scan3_k<<<dim3(DI / 16, NCH), 256, 0, stream>>>(
            delta, u, xdbl, alog, Sin, D_p + (size_t)L * DI, xr, ybf);

        {
            int n = NE * DI;
            f2b_k<<<(n / 4 + 255) / 256, 256, 0, stream>>>(out_w + (size_t)L * n, wbuf, n);
        }
        // out_proj accumulates directly into h (fuses the residual add)
        gemm_bt<<<(NE / 128) * (SEQ / 128), 256, 0, stream>>>(
            ybf, wbuf, h, SEQ, NE, DI, 1);
    }

    rmsnorm_k<<<SEQ, 256, 0, stream>>>(h, normf_w, normf_b, hf);

    gemm_bt<<<(VOCAB / 128) * (SEQ / 128), 256, 0, stream>>>(
        hf, Ebf, (float*)d_out, SEQ, VOCAB, NE, 0);
}

// Round 3
// 1169.120 us; speedup vs baseline: 1.3987x; 1.0212x over previous
//
#include <hip/hip_runtime.h>
#include <hip/hip_bf16.h>

#define SEQ   2048
#define NE    768
#define DI    1536
#define DS    16
#define DC    4
#define DTR   48
#define NL    2
#define VOCAB 32000
#define EPS   1e-5f
#define CHUNK 128
#define NCH   (SEQ / CHUNK)

typedef __hip_bfloat16 bf16;
typedef __bf16 bf16x8 __attribute__((ext_vector_type(8)));
typedef float  f32x4  __attribute__((ext_vector_type(4)));

#define GLOBAL_AS __attribute__((address_space(1)))
#define LDS_AS    __attribute__((address_space(3)))

// async global->LDS, 16 bytes per lane (global_load_lds_dwordx4)
__device__ __forceinline__ void gload16(const void* g, void* l)
{
    __builtin_amdgcn_global_load_lds((const GLOBAL_AS void*)g, (LDS_AS void*)l, 16, 0, 0);
}

#define BAR()   __builtin_amdgcn_s_barrier()
#define LGKM0() do { asm volatile("s_waitcnt lgkmcnt(0)" ::: "memory"); \
                     __builtin_amdgcn_sched_barrier(0); } while (0)
#define VMW(n)  do { asm volatile("s_waitcnt vmcnt(" #n ")" ::: "memory"); \
                     __builtin_amdgcn_sched_barrier(0); } while (0)

// ---------------------------------------------------------------------------
// fp32 -> bf16 conversion (for MFMA weight operands). n % 4 == 0.
// ---------------------------------------------------------------------------
__global__ __launch_bounds__(256) void f2b_k(const float* __restrict__ x,
    bf16* __restrict__ y, int n)
{
    int i = (blockIdx.x * 256 + threadIdx.x) * 4;
    if (i >= n) return;
    float4 v = *reinterpret_cast<const float4*>(x + i);
    y[i + 0] = __float2bfloat16(v.x);
    y[i + 1] = __float2bfloat16(v.y);
    y[i + 2] = __float2bfloat16(v.z);
    y[i + 3] = __float2bfloat16(v.w);
}

// ---------------------------------------------------------------------------
// Embedding gather: h[l,:] = E[tokens[l],:]  (fp32 in/out)
// ---------------------------------------------------------------------------
__global__ __launch_bounds__(256) void embed_k(const int* __restrict__ tok,
    const float* __restrict__ E, float* __restrict__ h)
{
    int l = blockIdx.x;
    int t = tok[l];
    for (int k = threadIdx.x; k < NE; k += 256)
        h[(size_t)l * NE + k] = E[(size_t)t * NE + k];
}

// ---------------------------------------------------------------------------
// RMSNorm over last dim (768), bf16 out for MFMA consumption
// ---------------------------------------------------------------------------
__global__ __launch_bounds__(256) void rmsnorm_k(const float* __restrict__ x,
    const float* __restrict__ w, const float* __restrict__ b, bf16* __restrict__ out)
{
    int l = blockIdx.x;
    const float* xr = x + (size_t)l * NE;
    float ss = 0.f;
    for (int k = threadIdx.x; k < NE; k += 256) { float v = xr[k]; ss += v * v; }
    for (int o = 32; o; o >>= 1) ss += __shfl_down(ss, o);
    __shared__ float s4[4];
    if ((threadIdx.x & 63) == 0) s4[threadIdx.x >> 6] = ss;
    __syncthreads();
    float inv = rsqrtf((s4[0] + s4[1] + s4[2] + s4[3]) / NE + EPS);
    for (int k = threadIdx.x; k < NE; k += 256)
        out[(size_t)l * NE + k] = __float2bfloat16(xr[k] * inv * w[k] + b[k]);
}

// ---------------------------------------------------------------------------
// 128x128 MFMA GEMM (m97 structure): used for in_proj / out_proj where the
// 256^2 kernel's grid would be too small. C[M,N] = A[M,K] @ B[N,K]^T.
// accum: 0 -> C = ; 1 -> C += (fuses residual add).
// ---------------------------------------------------------------------------
__global__ __launch_bounds__(256) void gemm_bt(const bf16* __restrict__ Abf,
    const bf16* __restrict__ Bbf, float* __restrict__ Cout, int M, int N, int K,
    int accum)
{
    __shared__ __align__(16) __bf16 As[128 * 32];
    __shared__ __align__(16) __bf16 Bs[128 * 32];

    const int nwg = gridDim.x;
    const int bid = blockIdx.x;
    const int q = nwg >> 3, r = nwg & 7;
    const int xcd = bid & 7, loc = bid >> 3;
    const int swz = (xcd < r ? xcd * (q + 1) : r * (q + 1) + (xcd - r) * q) + loc;
    const int mb = M >> 7;
    const int npan = swz / mb;
    const int mpan = swz - npan * mb;
    const int tm = mpan * 128;
    const int tn = npan * 128;

    const int tid  = threadIdx.x;
    const int wave = tid >> 6;
    const int lane = tid & 63;
    const int wm = wave >> 1, wn = wave & 1;
    const int r16 = lane & 15, quad = lane >> 4;

    const __bf16* A = reinterpret_cast<const __bf16*>(Abf);
    const __bf16* B = reinterpret_cast<const __bf16*>(Bbf);

    const int c0 = tid, c1 = tid + 256;
    const __bf16* ga0 = A + (size_t)(tm + (c0 >> 2)) * K + (c0 & 3) * 8;
    const __bf16* ga1 = A + (size_t)(tm + (c1 >> 2)) * K + (c1 & 3) * 8;
    const __bf16* gb0 = B + (size_t)(tn + (c0 >> 2)) * K + (c0 & 3) * 8;
    const __bf16* gb1 = B + (size_t)(tn + (c1 >> 2)) * K + (c1 & 3) * 8;
    __bf16* la0 = As + c0 * 8;
    __bf16* la1 = As + c1 * 8;
    __bf16* lb0 = Bs + c0 * 8;
    __bf16* lb1 = Bs + c1 * 8;

    f32x4 zero = {0.f, 0.f, 0.f, 0.f};
    f32x4 acc[4][4];
#pragma unroll
    for (int i = 0; i < 4; i++)
#pragma unroll
        for (int j = 0; j < 4; j++) acc[i][j] = zero;

    const int arow = wm * 64 + r16;
    const int brow = wn * 64 + r16;

    for (int kt = 0; kt < K; kt += 32) {
        __syncthreads();
        gload16(ga0 + kt, la0);
        gload16(ga1 + kt, la1);
        gload16(gb0 + kt, lb0);
        gload16(gb1 + kt, lb1);
        __syncthreads();

        bf16x8 av[4], bv[4];
#pragma unroll
        for (int i = 0; i < 4; i++)
            av[i] = *reinterpret_cast<const bf16x8*>(As + (arow + i * 16) * 32 + quad * 8);
#pragma unroll
        for (int j = 0; j < 4; j++)
            bv[j] = *reinterpret_cast<const bf16x8*>(Bs + (brow + j * 16) * 32 + quad * 8);
#pragma unroll
        for (int i = 0; i < 4; i++)
#pragma unroll
            for (int j = 0; j < 4; j++)
                acc[i][j] = __builtin_amdgcn_mfma_f32_16x16x32_bf16(av[i], bv[j], acc[i][j], 0, 0, 0);
    }

#pragma unroll
    for (int i = 0; i < 4; i++) {
        int cm0 = tm + wm * 64 + i * 16 + quad * 4;
#pragma unroll
        for (int j = 0; j < 4; j++) {
            int cn = tn + wn * 64 + j * 16 + r16;
            if (accum) {
#pragma unroll
                for (int rr = 0; rr < 4; rr++)
                    Cout[(size_t)(cm0 + rr) * N + cn] += acc[i][j][rr];
            } else {
#pragma unroll
                for (int rr = 0; rr < 4; rr++)
                    Cout[(size_t)(cm0 + rr) * N + cn] = acc[i][j][rr];
            }
        }
    }
}

// ---------------------------------------------------------------------------
// 256x256 8-phase MFMA GEMM (m201 template, plain HIP): C[M,N] = A@B^T.
// 512 thr = 8 waves (2 M x 4 N), BK=64, 128 KiB LDS double-buffer,
// st_16x32 XOR swizzle (inverse-swizzled global source + swizzled ds_read),
// counted vmcnt(6) at phases 4/8 only, setprio(1) around MFMA clusters.
// Per K-tile: 4 quadrant phases, frag reads {12,8,4,0} ds_read_b128.
// Requires M%256==0, N%256==0, K%128==0.
// ---------------------------------------------------------------------------
__device__ __forceinline__ void ld_a_set(const __bf16* ldsp, int base, int s,
    int r16, int quad, bf16x8 av[4][2])
{
    const int sw = (r16 & 4) << 2;           // 16-elem (32 B) XOR when row bit2
#pragma unroll
    for (int m = 0; m < 4; m++) {
        const int row = s * 64 + m * 16 + r16;
#pragma unroll
        for (int kk = 0; kk < 2; kk++) {
            const int off = base + row * 64 + ((kk * 32 + quad * 8) ^ sw);
            av[m][kk] = *reinterpret_cast<const bf16x8*>(ldsp + off);
        }
    }
}

__device__ __forceinline__ void ld_b_set(const __bf16* ldsp, int base, int rowbase,
    int nh, int r16, int quad, bf16x8 bv[2][2])
{
    const int sw = (r16 & 4) << 2;
#pragma unroll
    for (int n = 0; n < 2; n++) {
        const int row = rowbase + nh * 32 + n * 16 + r16;
#pragma unroll
        for (int kk = 0; kk < 2; kk++) {
            const int off = base + row * 64 + ((kk * 32 + quad * 8) ^ sw);
            bv[n][kk] = *reinterpret_cast<const bf16x8*>(ldsp + off);
        }
    }
}

#define MFMA_Q(AV, S, NH)                                                        \
    do {                                                                         \
        __builtin_amdgcn_s_setprio(1);                                           \
        _Pragma("unroll")                                                        \
        for (int m = 0; m < 4; m++)                                              \
            _Pragma("unroll")                                                    \
            for (int n = 0; n < 2; n++)                                          \
                _Pragma("unroll")                                                \
                for (int kk = 0; kk < 2; kk++)                                   \
                    acc[(S) * 4 + m][(NH) * 2 + n] =                             \
                        __builtin_amdgcn_mfma_f32_16x16x32_bf16(                 \
                            AV[m][kk], bv[n][kk],                                \
                            acc[(S) * 4 + m][(NH) * 2 + n], 0, 0, 0);            \
        __builtin_amdgcn_s_setprio(0);                                           \
    } while (0)

__global__ __launch_bounds__(512, 2) void gemm256(const bf16* __restrict__ Abf,
    const bf16* __restrict__ Bbf, float* __restrict__ Cout, int M, int N, int K)
{
    // per buffer (64 KB): [Ah0 | Ah1 | Bh0 | Bh1], each 128x64 bf16 = 16 KB
    __shared__ __align__(16) __bf16 lds[2 * 32768];

    const int tid  = threadIdx.x;
    const int wid  = tid >> 6;
    const int lane = tid & 63;
    const int wr = wid >> 2, wc = wid & 3;
    const int r16 = lane & 15, quad = lane >> 4;

    // block swizzle: M-inner + bijective XCD
    const int nwg = gridDim.x;
    const int bid = blockIdx.x;
    const int q = nwg >> 3, r = nwg & 7;
    const int xcd = bid & 7, loc = bid >> 3;
    const int swz = (xcd < r ? xcd * (q + 1) : r * (q + 1) + (xcd - r) * q) + loc;
    const int mb = M >> 8;
    const int npan = swz / mb;
    const int mpan = swz - npan * mb;
    const int tm = mpan * 256;
    const int tn = npan * 256;

    const __bf16* A = reinterpret_cast<const __bf16*>(Abf);
    const __bf16* B = reinterpret_cast<const __bf16*>(Bbf);

    // staging geometry: half-tile = 128 rows x 64 cols bf16 = 1024 x 16B chunks.
    // thread stages rows ra and ra+64 at (inverse-)swizzled source column.
    const int ra = tid >> 3;
    const int ca = ((tid & 7) * 8) ^ ((ra & 4) << 2);

    auto stA = [&](int h, int t, int b) {
        const __bf16* s0 = A + (size_t)(tm + h * 128 + ra) * K + t * 64 + ca;
        __bf16* d = lds + b * 32768 + h * 8192;
        gload16(s0, d + tid * 8);
        gload16(s0 + (size_t)64 * K, d + (tid + 512) * 8);
    };
    auto stB = [&](int h, int t, int b) {
        const __bf16* s0 = B + (size_t)(tn + h * 128 + ra) * K + t * 64 + ca;
        __bf16* d = lds + b * 32768 + 16384 + h * 8192;
        gload16(s0, d + tid * 8);
        gload16(s0 + (size_t)64 * K, d + (tid + 512) * 8);
    };

    const int abase0 = wr * 8192;                         // buf0 A base
    const int abase1 = 32768 + wr * 8192;                 // buf1 A base
    const int bbase0 = 16384 + (wc >> 1) * 8192;          // buf0 B base
    const int bbase1 = 32768 + 16384 + (wc >> 1) * 8192;  // buf1 B base
    const int browb  = (wc & 1) * 64;

    f32x4 zero = {0.f, 0.f, 0.f, 0.f};
    f32x4 acc[8][4];
#pragma unroll
    for (int i = 0; i < 8; i++)
#pragma unroll
        for (int j = 0; j < 4; j++) acc[i][j] = zero;

    bf16x8 av0[4][2], av1[4][2], bv[2][2];

    const int NIT = K >> 7;   // K / 128, two K-tiles per iteration

    // prologue: T0 all 4 halves + T1 {Ah0,Ah1,Bh0} = 14 loads; land T0's 8.
    stA(0, 0, 0); stA(1, 0, 0); stB(0, 0, 0); stB(1, 0, 0);
    stA(0, 1, 1); stA(1, 1, 1); stB(0, 1, 1);
    VMW(6);
    BAR();

    for (int it = 0; it < NIT; ++it) {
        const int t1 = 2 * it + 1, u0 = 2 * it + 2, u1 = 2 * it + 3;
        const bool pf = (it + 1 < NIT);
        // ---- K-tile T0 (buf0) ----
        // P1: 12 ds_reads, stage T1.Bh1
        ld_a_set(lds, abase0, 0, r16, quad, av0);
        ld_b_set(lds, bbase0, browb, 0, r16, quad, bv);
        stB(1, t1, 1);
        BAR(); LGKM0();
        MFMA_Q(av0, 0, 0);
        BAR();
        // P2: 8 ds_reads
        ld_a_set(lds, abase0, 1, r16, quad, av1);
        BAR(); LGKM0();
        MFMA_Q(av1, 1, 0);
        BAR();
        // P3: 4 ds_reads, stage U0.Ah0+Ah1
        ld_b_set(lds, bbase0, browb, 1, r16, quad, bv);
        if (pf) { stA(0, u0, 0); stA(1, u0, 0); }
        BAR(); LGKM0();
        MFMA_Q(av1, 1, 1);
        BAR();
        // P4: stage U0.Bh0, per-tile vmcnt (drain on last iteration)
        if (pf) stB(0, u0, 0);
        if (pf) { VMW(6); } else { VMW(0); }
        BAR(); LGKM0();
        MFMA_Q(av0, 0, 1);
        BAR();
        // ---- K-tile T1 (buf1) ----
        // P5
        ld_a_set(lds, abase1, 0, r16, quad, av0);
        ld_b_set(lds, bbase1, browb, 0, r16, quad, bv);
        if (pf) stB(1, u0, 0);
        BAR(); LGKM0();
        MFMA_Q(av0, 0, 0);
        BAR();
        // P6
        ld_a_set(lds, abase1, 1, r16, quad, av1);
        BAR(); LGKM0();
        MFMA_Q(av1, 1, 0);
        BAR();
        // P7
        ld_b_set(lds, bbase1, browb, 1, r16, quad, bv);
        if (pf) { stA(0, u1, 1); stA(1, u1, 1); }
        BAR(); LGKM0();
        MFMA_Q(av1, 1, 1);
        BAR();
        // P8
        if (pf) { stB(0, u1, 1); VMW(6); }
        BAR(); LGKM0();
        MFMA_Q(av0, 0, 1);
        BAR();
    }

    // epilogue: C write
#pragma unroll
    for (int s = 0; s < 2; s++)
#pragma unroll
        for (int m = 0; m < 4; m++) {
            int cm0 = tm + wr * 128 + s * 64 + m * 16 + quad * 4;
#pragma unroll
            for (int nh = 0; nh < 2; nh++)
#pragma unroll
                for (int n = 0; n < 2; n++) {
                    int cn = tn + wc * 64 + nh * 32 + n * 16 + r16;
#pragma unroll
                    for (int rr = 0; rr < 4; rr++)
                        Cout[(size_t)(cm0 + rr) * N + cn] = acc[s * 4 + m][nh * 2 + n][rr];
                }
        }
}

// ---------------------------------------------------------------------------
// Depthwise causal conv (k=4) + bias + SiLU.
// ---------------------------------------------------------------------------
__global__ __launch_bounds__(256) void conv_silu_k(const float* __restrict__ xr,
    const float* __restrict__ cw, const float* __restrict__ cb, float* __restrict__ u)
{
    int idx = blockIdx.x * 256 + threadIdx.x;   // over SEQ*DI
    int l = idx / DI, d = idx - l * DI;
    float s = cb[d];
#pragma unroll
    for (int t = 0; t < DC; t++) {
        int ls = l - (DC - 1) + t;
        if (ls >= 0) s += xr[(size_t)ls * (2 * DI) + d] * cw[d * DC + t];
    }
    u[idx] = s / (1.f + expf(-s));
}

// ---------------------------------------------------------------------------
// x_proj: xdbl[l, j] = sum_k u[l,k] * xpw[j,k], j < 80.
// Block per l: u[l] staged in LDS once (kills the 80x u re-read);
// each of 4 waves computes 20 j's with float4 loads of xpw.
// ---------------------------------------------------------------------------
__global__ __launch_bounds__(256) void xproj_k(const float* __restrict__ u,
    const float* __restrict__ xpw, float* __restrict__ xdbl)
{
    __shared__ float us[DI];
    int l = blockIdx.x;
    const float4* ur = reinterpret_cast<const float4*>(u + (size_t)l * DI);
#pragma unroll
    for (int k = threadIdx.x; k < DI / 4; k += 256)
        *reinterpret_cast<float4*>(&us[k * 4]) = ur[k];
    __syncthreads();
    int w = threadIdx.x >> 6, lane = threadIdx.x & 63;
    for (int jj = 0; jj < 20; jj++) {
        int j = w * 20 + jj;
        const float4* wr4 = reinterpret_cast<const float4*>(xpw + (size_t)j * DI);
        float s = 0.f;
#pragma unroll
        for (int k = lane; k < DI / 4; k += 64) {
            float4 a = *reinterpret_cast<const float4*>(&us[k * 4]);
            float4 b = wr4[k];
            s += a.x * b.x + a.y * b.y + a.z * b.z + a.w * b.w;
        }
        for (int o = 32; o; o >>= 1) s += __shfl_down(s, o);
        if (lane == 0) xdbl[(size_t)l * 80 + j] = s;
    }
}

// ---------------------------------------------------------------------------
// dt_proj + softplus. Weights held in registers (48/thread); each block owns
// 256 d-channels and loops 32 sequence rows, sharing xs[48] via LDS.
// Grid (DI/256, SEQ/32).
// ---------------------------------------------------------------------------
__global__ __launch_bounds__(256) void dtproj_k(const float* __restrict__ xdbl,
    const float* __restrict__ dtw, const float* __restrict__ dtb, float* __restrict__ delta)
{
    int d = blockIdx.x * 256 + threadIdx.x;
    float w[DTR];
    const float* wr = dtw + (size_t)d * DTR;
#pragma unroll
    for (int k = 0; k < DTR; k++) w[k] = wr[k];
    float bv = dtb[d];
    __shared__ float xs[DTR];
    int l0 = blockIdx.y * 32;
    for (int li = 0; li < 32; li++) {
        int l = l0 + li;
        __syncthreads();
        if (threadIdx.x < DTR) xs[threadIdx.x] = xdbl[(size_t)l * 80 + threadIdx.x];
        __syncthreads();
        float s = bv;
#pragma unroll
        for (int k = 0; k < DTR; k++) s += xs[k] * w[k];
        delta[(size_t)l * DI + d] = fmaxf(s, 0.f) + log1pf(expf(-fabsf(s)));
    }
}

// ---------------------------------------------------------------------------
// Chunked selective scan, pass 1.
// ---------------------------------------------------------------------------
__global__ __launch_bounds__(256) void scan1_k(const float* __restrict__ delta,
    const float* __restrict__ u, const float* __restrict__ xdbl,
    const float* __restrict__ alog, float* __restrict__ S, float* __restrict__ P)
{
    int dg = threadIdx.x >> 4, n = threadIdx.x & 15;
    int d = blockIdx.x * 16 + dg;
    int c = blockIdx.y;
    float A = -expf(alog[(size_t)d * DS + n]);
    float st = 0.f, pr = 1.f;
    int l0 = c * CHUNK;
#pragma unroll 4
    for (int t = 0; t < CHUNK; t++) {
        int l = l0 + t;
        float dl = delta[(size_t)l * DI + d];
        float ul = u[(size_t)l * DI + d];
        float Bn = xdbl[(size_t)l * 80 + DTR + n];
        float a = expf(dl * A);
        st = a * st + dl * ul * Bn;
        pr *= a;
    }
    size_t o = ((size_t)c * DI + d) * DS + n;
    S[o] = st;
    P[o] = pr;
}

// ---------------------------------------------------------------------------
// Pass 2: sequential combine over the 16 chunks -> incoming state per chunk.
// ---------------------------------------------------------------------------
__global__ __launch_bounds__(256) void scan2_k(const float* __restrict__ S,
    const float* __restrict__ P, float* __restrict__ sin_)
{
    int i = blockIdx.x * 256 + threadIdx.x;   // over DI*DS
    float run = 0.f;
#pragma unroll
    for (int c = 0; c < NCH; c++) {
        size_t o = (size_t)c * DI * DS + i;
        sin_[o] = run;
        run = S[o] + P[o] * run;
    }
}

// ---------------------------------------------------------------------------
// Pass 3: re-run each chunk from its incoming state, compute y, fuse
// (y + u*D) * silu(res) gate, write bf16 for the out_proj GEMM.
// ---------------------------------------------------------------------------
__global__ __launch_bounds__(256) void scan3_k(const float* __restrict__ delta,
    const float* __restrict__ u, const float* __restrict__ xdbl,
    const float* __restrict__ alog, const float* __restrict__ sin_,
    const float* __restrict__ Dp, const float* __restrict__ xr,
    bf16* __restrict__ ybf)
{
    int dg = threadIdx.x >> 4, n = threadIdx.x & 15;
    int d = blockIdx.x * 16 + dg;
    int c = blockIdx.y;
    float A = -expf(alog[(size_t)d * DS + n]);
    float Dv = Dp[d];
    float st = sin_[((size_t)c * DI + d) * DS + n];
    int l0 = c * CHUNK;
#pragma unroll 2
    for (int t = 0; t < CHUNK; t++) {
        int l = l0 + t;
        float dl = delta[(size_t)l * DI + d];
        float ul = u[(size_t)l * DI + d];
        float Bn = xdbl[(size_t)l * 80 + DTR + n];
        float Cn = xdbl[(size_t)l * 80 + DTR + DS + n];
        float a = expf(dl * A);
        st = a * st + dl * ul * Bn;
        float p = st * Cn;
        p += __shfl_down(p, 8);
        p += __shfl_down(p, 4);
        p += __shfl_down(p, 2);
        p += __shfl_down(p, 1);
        if (n == 0) {
            float r = xr[(size_t)l * (2 * DI) + DI + d];
            float yv = (p + ul * Dv) * (r / (1.f + expf(-r)));
            ybf[(size_t)l * DI + d] = __float2bfloat16(yv);
        }
    }
}

// ---------------------------------------------------------------------------
extern "C" void kernel_launch(void* const* d_in, const int* in_sizes, int n_in,
                              void* d_out, int out_size, void* d_ws, size_t ws_size,
                              hipStream_t stream)
{
    const int*   tokens  = (const int*)  d_in[0];
    const float* E       = (const float*)d_in[1];
    const float* in_w    = (const float*)d_in[2];
    const float* conv_w  = (const float*)d_in[3];
    const float* conv_b  = (const float*)d_in[4];
    const float* xp_w    = (const float*)d_in[5];
    const float* dt_w    = (const float*)d_in[6];
    const float* dt_b    = (const float*)d_in[7];
    const float* A_log   = (const float*)d_in[8];
    const float* D_p     = (const float*)d_in[9];
    const float* out_w   = (const float*)d_in[10];
    const float* norm_w  = (const float*)d_in[11];
    const float* norm_b  = (const float*)d_in[12];
    const float* normf_w = (const float*)d_in[13];
    const float* normf_b = (const float*)d_in[14];

    char* ws = (char*)d_ws;
    size_t off = 0;
    auto alloc = [&](size_t bytes) -> void* {
        void* p = ws + off;
        off = (off + bytes + 255) & ~(size_t)255;
        return p;
    };

    float* h     = (float*)alloc((size_t)SEQ * NE * 4);
    bf16*  xn    = (bf16*) alloc((size_t)SEQ * NE * 2);
    float* xr    = (float*)alloc((size_t)SEQ * 2 * DI * 4);
    float* u     = (float*)alloc((size_t)SEQ * DI * 4);
    float* xdbl  = (float*)alloc((size_t)SEQ * 80 * 4);
    float* delta = (float*)alloc((size_t)SEQ * DI * 4);
    bf16*  ybf   = (bf16*) alloc((size_t)SEQ * DI * 2);
    bf16*  hf    = (bf16*) alloc((size_t)SEQ * NE * 2);
    bf16*  Ebf   = (bf16*) alloc((size_t)VOCAB * NE * 2);           // 49 MB
    bf16*  wbuf  = (bf16*) alloc((size_t)2 * DI * NE * 2);          // reused proj weights
    float* Sbuf  = (float*)alloc((size_t)NCH * DI * DS * 4);
    float* Pbuf  = (float*)alloc((size_t)NCH * DI * DS * 4);
    float* Sin   = (float*)alloc((size_t)NCH * DI * DS * 4);

    {
        int n = VOCAB * NE;
        f2b_k<<<(n / 4 + 255) / 256, 256, 0, stream>>>(E, Ebf, n);
    }

    embed_k<<<SEQ, 256, 0, stream>>>(tokens, E, h);

    for (int L = 0; L < NL; L++) {
        rmsnorm_k<<<SEQ, 256, 0, stream>>>(h, norm_w + (size_t)L * NE, norm_b + (size_t)L * NE, xn);

        {
            int n = 2 * DI * NE;
            f2b_k<<<(n / 4 + 255) / 256, 256, 0, stream>>>(in_w + (size_t)L * n, wbuf, n);
        }
        gemm_bt<<<(2 * DI / 128) * (SEQ / 128), 256, 0, stream>>>(
            xn, wbuf, xr, SEQ, 2 * DI, NE, 0);

        conv_silu_k<<<SEQ * DI / 256, 256, 0, stream>>>(
            xr, conv_w + (size_t)L * DI * DC, conv_b + (size_t)L * DI, u);

        xproj_k<<<SEQ, 256, 0, stream>>>(u, xp_w + (size_t)L * 80 * DI, xdbl);

        dtproj_k<<<dim3(DI / 256, SEQ / 32), 256, 0, stream>>>(
            xdbl, dt_w + (size_t)L * DI * DTR, dt_b + (size_t)L * DI, delta);

        const float* alog = A_log + (size_t)L * DI * DS;
        scan1_k<<<dim3(DI / 16, NCH), 256, 0, stream>>>(delta, u, xdbl, alog, Sbuf, Pbuf);
        scan2_k<<<DI * DS / 256, 256, 0, stream>>>(Sbuf, Pbuf, Sin);
        scan3_k<<<dim3(DI / 16, NCH), 256, 0, stream>>>(
            delta, u, xdbl, alog, Sin, D_p + (size_t)L * DI, xr, ybf);

        {
            int n = NE * DI;
            f2b_k<<<(n / 4 + 255) / 256, 256, 0, stream>>>(out_w + (size_t)L * n, wbuf, n);
        }
        // out_proj accumulates directly into h (fuses the residual add)
        gemm_bt<<<(NE / 128) * (SEQ / 128), 256, 0, stream>>>(
            ybf, wbuf, h, SEQ, NE, DI, 1);
    }

    rmsnorm_k<<<SEQ, 256, 0, stream>>>(h, normf_w, normf_b, hf);

    gemm256<<<(VOCAB / 256) * (SEQ / 256), 512, 0, stream>>>(
        hf, Ebf, (float*)d_out, SEQ, VOCAB, NE);
}